// Round 1
// baseline (739.523 us; speedup 1.0000x reference)
//
#include <hip/hip_runtime.h>
#include <math.h>

#define N_ATOM 2048
#define NTOK   512
#define CC     128
#define CZDIM  16
#define HH     4
#define CHD    32
#define NHID   256
#define NQB    64     // 2048 / 32 query blocks
#define R1     8      // rows per workgroup in K1/K3

__device__ __forceinline__ float sigm(float x) { return 1.0f / (1.0f + __expf(-x)); }

// ---------------------------------------------------------------------------
// amask_bias[l] = (sum_i a2t[l,i]*tm[i] - 1) * 1e9     (additive key mask)
// 4 rows per block, one wave per row, coalesced reads.
__global__ __launch_bounds__(256) void k_amask(const float* __restrict__ a2t,
                                               const float* __restrict__ tm,
                                               float* __restrict__ amask) {
    int wave = threadIdx.x >> 6, lane = threadIdx.x & 63;
    int l = blockIdx.x * 4 + wave;
    float s = 0.0f;
    for (int i = lane; i < NTOK; i += 64) s += a2t[(size_t)l * NTOK + i] * tm[i];
    for (int m = 1; m < 64; m <<= 1) s += __shfl_xor(s, m);
    if (lane == 0) amask[l] = (s - 1.0f) * 1e9f;
}

// ---------------------------------------------------------------------------
// K1: per-row AdaLN (both) + all row matvecs.
// grid 256 (8 rows each), block 256.
__global__ __launch_bounds__(256) void k_adaln_proj(
    const float* __restrict__ a, const float* __restrict__ cl,
    const float* __restrict__ gs1, const float* __restrict__ ws1,
    const float* __restrict__ bs1, const float* __restrict__ wsb1,
    const float* __restrict__ wq, const float* __restrict__ bq,
    const float* __restrict__ wk, const float* __restrict__ wv,
    const float* __restrict__ wg,
    const float* __restrict__ wog1, const float* __restrict__ bog1,
    const float* __restrict__ gs2, const float* __restrict__ ws2,
    const float* __restrict__ bs2, const float* __restrict__ wsb2,
    const float* __restrict__ wt1, const float* __restrict__ wt2,
    const float* __restrict__ wt3,
    const float* __restrict__ wog2, const float* __restrict__ bog2,
    float* __restrict__ q_o, float* __restrict__ k_o, float* __restrict__ v_o,
    float* __restrict__ g_o, float* __restrict__ og1_o, float* __restrict__ trans_o) {
    __shared__ float lna[R1][CC];   // LN(a)
    __shared__ float sn1[R1][CC];   // LN(cl)*gs1
    __shared__ float sn2[R1][CC];   // LN(cl)*gs2
    __shared__ float cls[R1][CC];   // raw cl
    __shared__ float aln1[R1][CC];  // AdaLN1 output
    __shared__ float a2s[R1][CC];   // AdaLN2 output
    __shared__ float hid[R1][NHID]; // SwiGLU hidden

    const int t = threadIdx.x;
    const int n0 = blockIdx.x * R1;

    for (int idx = t; idx < R1 * CC; idx += 256) {
        lna[idx >> 7][idx & 127] = a[n0 * CC + idx];
        cls[idx >> 7][idx & 127] = cl[n0 * CC + idx];
    }
    __syncthreads();

    { // LayerNorms: 32 lanes per row (2 rows per wave), wave-lockstep in-place.
        int r = t >> 5, l = t & 31;
        float s = 0, s2 = 0;
        for (int k = 0; k < 4; k++) { float x = lna[r][l + 32 * k]; s += x; s2 += x * x; }
        for (int m = 1; m < 32; m <<= 1) { s += __shfl_xor(s, m); s2 += __shfl_xor(s2, m); }
        float mean = s * (1.0f / 128.0f);
        float rs = rsqrtf(s2 * (1.0f / 128.0f) - mean * mean + 1e-5f);
        float cs = 0, cs2 = 0;
        for (int k = 0; k < 4; k++) { float x = cls[r][l + 32 * k]; cs += x; cs2 += x * x; }
        for (int m = 1; m < 32; m <<= 1) { cs += __shfl_xor(cs, m); cs2 += __shfl_xor(cs2, m); }
        float cmean = cs * (1.0f / 128.0f);
        float crs = rsqrtf(cs2 * (1.0f / 128.0f) - cmean * cmean + 1e-5f);
        for (int k = 0; k < 4; k++) {
            int c = l + 32 * k;
            lna[r][c] = (lna[r][c] - mean) * rs;
            float cn = (cls[r][c] - cmean) * crs;
            sn1[r][c] = cn * gs1[c];
            sn2[r][c] = cn * gs2[c];
        }
    }
    __syncthreads();

    const int o = t & 127;
    const int rb = (t >> 7) * 4;  // 4 rows per thread

    { // AdaLN1: aln1 = sigmoid(sn1@ws1+bs1)*lna + sn1@wsb1
        float A[4] = {0, 0, 0, 0}, Bv[4] = {0, 0, 0, 0};
        for (int c = 0; c < CC; c++) {
            float w1 = ws1[c * CC + o], w2 = wsb1[c * CC + o];
#pragma unroll
            for (int r = 0; r < 4; r++) { float x = sn1[rb + r][c]; A[r] += x * w1; Bv[r] += x * w2; }
        }
        float bb = bs1[o];
        for (int r = 0; r < 4; r++) aln1[rb + r][o] = sigm(A[r] + bb) * lna[rb + r][o] + Bv[r];
    }
    { // AdaLN2 -> a2s
        float A[4] = {0, 0, 0, 0}, Bv[4] = {0, 0, 0, 0};
        for (int c = 0; c < CC; c++) {
            float w1 = ws2[c * CC + o], w2 = wsb2[c * CC + o];
#pragma unroll
            for (int r = 0; r < 4; r++) { float x = sn2[rb + r][c]; A[r] += x * w1; Bv[r] += x * w2; }
        }
        float bb = bs2[o];
        for (int r = 0; r < 4; r++) a2s[rb + r][o] = sigm(A[r] + bb) * lna[rb + r][o] + Bv[r];
    }
    __syncthreads();

    { // q,k,v,g projections from aln1
        float Aq[4] = {0, 0, 0, 0}, Ak[4] = {0, 0, 0, 0}, Av[4] = {0, 0, 0, 0}, Ag[4] = {0, 0, 0, 0};
        for (int c = 0; c < CC; c++) {
            float wqv = wq[c * CC + o], wkv = wk[c * CC + o], wvv = wv[c * CC + o], wgv = wg[c * CC + o];
#pragma unroll
            for (int r = 0; r < 4; r++) {
                float x = aln1[rb + r][c];
                Aq[r] += x * wqv; Ak[r] += x * wkv; Av[r] += x * wvv; Ag[r] += x * wgv;
            }
        }
        float bqv = bq[o];
        for (int r = 0; r < 4; r++) {
            int n = n0 + rb + r;
            q_o[n * CC + o] = Aq[r] + bqv;
            k_o[n * CC + o] = Ak[r];
            v_o[n * CC + o] = Av[r];
            g_o[n * CC + o] = sigm(Ag[r]);
        }
    }
    { // og1 = sigmoid(cl @ wog1 + bog1)
        float A[4] = {0, 0, 0, 0};
        for (int c = 0; c < CC; c++) {
            float w = wog1[c * CC + o];
#pragma unroll
            for (int r = 0; r < 4; r++) A[r] += cls[rb + r][c] * w;
        }
        float bb = bog1[o];
        for (int r = 0; r < 4; r++) og1_o[(n0 + rb + r) * CC + o] = sigm(A[r] + bb);
    }
    { // transition hidden: silu(a2@wt1) * (a2@wt2); thread t owns hidden col t for all 8 rows
        float A[8] = {0, 0, 0, 0, 0, 0, 0, 0};
        for (int c = 0; c < CC; c++) {
            float w = wt1[c * NHID + t];
#pragma unroll
            for (int r = 0; r < 8; r++) A[r] += a2s[r][c] * w;
        }
#pragma unroll
        for (int r = 0; r < 8; r++) { float x = A[r]; hid[r][t] = x * sigm(x); }
        float B[8] = {0, 0, 0, 0, 0, 0, 0, 0};
        for (int c = 0; c < CC; c++) {
            float w = wt2[c * NHID + t];
#pragma unroll
            for (int r = 0; r < 8; r++) B[r] += a2s[r][c] * w;
        }
#pragma unroll
        for (int r = 0; r < 8; r++) hid[r][t] *= B[r];
    }
    __syncthreads();
    { // trans = sigmoid(cl@wog2+bog2) * (hid @ wt3)
        float A[4] = {0, 0, 0, 0}, G[4] = {0, 0, 0, 0};
        for (int c = 0; c < NHID; c++) {
            float w = wt3[c * CC + o];
#pragma unroll
            for (int r = 0; r < 4; r++) A[r] += hid[rb + r][c] * w;
        }
        for (int c = 0; c < CC; c++) {
            float w = wog2[c * CC + o];
#pragma unroll
            for (int r = 0; r < 4; r++) G[r] += cls[rb + r][c] * w;
        }
        float bb = bog2[o];
        for (int r = 0; r < 4; r++)
            trans_o[(n0 + rb + r) * CC + o] = sigm(G[r] + bb) * A[r];
    }
}

// ---------------------------------------------------------------------------
// K_pb: sparse pair bias. One thread per (qb,qi,kj) pair: LN over 16 channels + 4 dots.
// grid 1024, block 256. Reads only the 128-wide key window of plm.
__global__ __launch_bounds__(256) void k_pb(const float* __restrict__ plm,
                                            const float* __restrict__ gz,
                                            const float* __restrict__ bz,
                                            const float* __restrict__ wz,
                                            float* __restrict__ pb) {
    int pid = blockIdx.x * 256 + threadIdx.x;  // 64*32*128 total
    int qb = pid >> 12;
    int qi = (pid >> 7) & 31;
    int kj = pid & 127;
    int n = qb * 32 + qi;
    int kstart = max(0, qb * 32 - 48);
    int m = kstart + kj;
    float out[HH] = {0, 0, 0, 0};
    if (m < N_ATOM) {
        const float* p = plm + ((size_t)n * N_ATOM + m) * CZDIM;
        float x[CZDIM];
        const float4* p4 = (const float4*)p;
#pragma unroll
        for (int i = 0; i < 4; i++) {
            float4 v = p4[i];
            x[4 * i] = v.x; x[4 * i + 1] = v.y; x[4 * i + 2] = v.z; x[4 * i + 3] = v.w;
        }
        float s = 0, s2 = 0;
#pragma unroll
        for (int c = 0; c < CZDIM; c++) { s += x[c]; s2 += x[c] * x[c]; }
        float mean = s * (1.0f / 16.0f);
        float rs = rsqrtf(s2 * (1.0f / 16.0f) - mean * mean + 1e-5f);
#pragma unroll
        for (int c = 0; c < CZDIM; c++) {
            float z = (x[c] - mean) * rs * gz[c] + bz[c];
#pragma unroll
            for (int h = 0; h < HH; h++) out[h] += z * wz[c * HH + h];
        }
    }
#pragma unroll
    for (int h = 0; h < HH; h++)
        pb[(((qb * HH + h) * 32 + qi) << 7) + kj] = out[h];
}

// ---------------------------------------------------------------------------
// K_attn: one workgroup per (query block, head). 32 queries x <=128 keys.
__global__ __launch_bounds__(256) void k_attn(const float* __restrict__ q,
                                              const float* __restrict__ k,
                                              const float* __restrict__ v,
                                              const float* __restrict__ pb,
                                              const float* __restrict__ amask,
                                              float* __restrict__ o_out) {
    __shared__ __align__(16) float qs[32][36];
    __shared__ __align__(16) float ks[128][36];
    __shared__ __align__(16) float vs[128][36];
    __shared__ float ps[32][132];
    const int t = threadIdx.x;
    const int qb = blockIdx.x >> 2, h = blockIdx.x & 3;
    const int n0 = qb * 32;
    const int kstart = max(0, qb * 32 - 48);
    const int nk = min(N_ATOM, qb * 32 + 80) - kstart;

    for (int idx = t; idx < 32 * 32; idx += 256) {
        int qi = idx >> 5, d = idx & 31;
        qs[qi][d] = q[(n0 + qi) * CC + h * CHD + d];
    }
    for (int idx = t; idx < 128 * 32; idx += 256) {
        int kj = idx >> 5, d = idx & 31;
        int m = kstart + kj;
        float kv = 0.0f, vv = 0.0f;
        if (m < N_ATOM) { kv = k[m * CC + h * CHD + d]; vv = v[m * CC + h * CHD + d]; }
        ks[kj][d] = kv; vs[kj][d] = vv;
    }
    __syncthreads();

    const int qi = t >> 3, j8 = t & 7;  // 8 threads per query row (same wave)
    const float isc = 0.17677669529663687f;  // 1/sqrt(32)
    const float* pbrow = pb + ((qb * HH + h) * 32 + qi) * 128;
    float lr[16];
    float mx = -1e30f;
#pragma unroll
    for (int jj = 0; jj < 16; jj++) {
        int kj = j8 + 8 * jj;
        float acc = 0;
#pragma unroll
        for (int d = 0; d < CHD; d++) acc += qs[qi][d] * ks[kj][d];
        float l = (kj < nk) ? (acc * isc + pbrow[kj] + amask[kstart + kj]) : -1e9f;
        lr[jj] = l;
        mx = fmaxf(mx, l);
    }
    for (int m = 1; m < 8; m <<= 1) mx = fmaxf(mx, __shfl_xor(mx, m));
    float sum = 0;
#pragma unroll
    for (int jj = 0; jj < 16; jj++) { lr[jj] = __expf(lr[jj] - mx); sum += lr[jj]; }
    for (int m = 1; m < 8; m <<= 1) sum += __shfl_xor(sum, m);
    float rd = 1.0f / sum;
#pragma unroll
    for (int jj = 0; jj < 16; jj++) ps[qi][j8 + 8 * jj] = lr[jj] * rd;
    __syncthreads();

    const int d0 = (t & 7) * 4;
    float4 acc = {0, 0, 0, 0};
    for (int kj = 0; kj < 128; kj++) {
        float p = ps[qi][kj];
        float4 vv = *(const float4*)&vs[kj][d0];
        acc.x += p * vv.x; acc.y += p * vv.y; acc.z += p * vv.z; acc.w += p * vv.w;
    }
    *(float4*)&o_out[(n0 + qi) * CC + h * CHD + d0] = acc;
}

// ---------------------------------------------------------------------------
// K3: a_new = og1 * ((g*o) @ wo) + trans
__global__ __launch_bounds__(256) void k_combine(const float* __restrict__ g,
                                                 const float* __restrict__ o_in,
                                                 const float* __restrict__ og1,
                                                 const float* __restrict__ trans,
                                                 const float* __restrict__ wo,
                                                 float* __restrict__ a_out) {
    __shared__ float gos[R1][CC];
    const int t = threadIdx.x;
    const int n0 = blockIdx.x * R1;
    for (int idx = t; idx < R1 * CC; idx += 256)
        gos[idx >> 7][idx & 127] = g[n0 * CC + idx] * o_in[n0 * CC + idx];
    __syncthreads();
    const int o = t & 127, rb = (t >> 7) * 4;
    float A[4] = {0, 0, 0, 0};
    for (int c = 0; c < CC; c++) {
        float w = wo[c * CC + o];
#pragma unroll
        for (int r = 0; r < 4; r++) A[r] += gos[rb + r][c] * w;
    }
    for (int r = 0; r < 4; r++) {
        int n = n0 + rb + r;
        a_out[n * CC + o] = og1[n * CC + o] * A[r] + trans[n * CC + o];
    }
}

// ---------------------------------------------------------------------------
extern "C" void kernel_launch(void* const* d_in, const int* in_sizes, int n_in,
                              void* d_out, int out_size, void* d_ws, size_t ws_size,
                              hipStream_t stream) {
    const float* ql   = (const float*)d_in[0];
    const float* cl   = (const float*)d_in[1];
    const float* plm  = (const float*)d_in[2];
    const float* a2t  = (const float*)d_in[3];
    const float* tm   = (const float*)d_in[4];
    const float* ada1_gs  = (const float*)d_in[5];
    const float* ada1_ws  = (const float*)d_in[6];
    const float* ada1_bs  = (const float*)d_in[7];
    const float* ada1_wsb = (const float*)d_in[8];
    const float* wq  = (const float*)d_in[9];
    const float* bq  = (const float*)d_in[10];
    const float* wk  = (const float*)d_in[11];
    const float* wv  = (const float*)d_in[12];
    const float* gz  = (const float*)d_in[13];
    const float* bz  = (const float*)d_in[14];
    const float* wz  = (const float*)d_in[15];
    const float* wg  = (const float*)d_in[16];
    const float* wo  = (const float*)d_in[17];
    const float* wog1 = (const float*)d_in[18];
    const float* bog1 = (const float*)d_in[19];
    const float* ada2_gs  = (const float*)d_in[20];
    const float* ada2_ws  = (const float*)d_in[21];
    const float* ada2_bs  = (const float*)d_in[22];
    const float* ada2_wsb = (const float*)d_in[23];
    const float* wt1 = (const float*)d_in[24];
    const float* wt2 = (const float*)d_in[25];
    const float* wt3 = (const float*)d_in[26];
    const float* wog2 = (const float*)d_in[27];
    const float* bog2 = (const float*)d_in[28];

    const size_t NC = (size_t)N_ATOM * CC;  // 262144
    float* ws = (float*)d_ws;
    float* a_cur  = ws;
    float* qb_    = ws + 1 * NC;
    float* kb_    = ws + 2 * NC;
    float* vb_    = ws + 3 * NC;
    float* gb_    = ws + 4 * NC;
    float* og1b_  = ws + 5 * NC;
    float* transb = ws + 6 * NC;
    float* ob_    = ws + 7 * NC;
    float* pbb_   = ws + 8 * NC;                 // 64*4*32*128 = 1048576 floats
    float* amaskb = ws + 8 * NC + 1048576;       // 2048 floats

    hipMemcpyAsync(a_cur, ql, NC * sizeof(float), hipMemcpyDeviceToDevice, stream);
    k_amask<<<N_ATOM / 4, 256, 0, stream>>>(a2t, tm, amaskb);

    for (int b = 0; b < 3; b++) {
        k_adaln_proj<<<N_ATOM / R1, 256, 0, stream>>>(
            a_cur, cl,
            ada1_gs + b * CC, ada1_ws + b * CC * CC, ada1_bs + b * CC, ada1_wsb + b * CC * CC,
            wq + b * CC * CC, bq + b * CC, wk + b * CC * CC, wv + b * CC * CC, wg + b * CC * CC,
            wog1 + b * CC * CC, bog1 + b * CC,
            ada2_gs + b * CC, ada2_ws + b * CC * CC, ada2_bs + b * CC, ada2_wsb + b * CC * CC,
            wt1 + b * CC * NHID, wt2 + b * CC * NHID, wt3 + b * NHID * CC,
            wog2 + b * CC * CC, bog2 + b * CC,
            qb_, kb_, vb_, gb_, og1b_, transb);
        k_pb<<<1024, 256, 0, stream>>>(plm, gz + b * CZDIM, bz + b * CZDIM,
                                       wz + b * CZDIM * HH, pbb_);
        k_attn<<<NQB * HH, 256, 0, stream>>>(qb_, kb_, vb_, pbb_, amaskb, ob_);
        k_combine<<<N_ATOM / R1, 256, 0, stream>>>(gb_, ob_, og1b_, transb,
                                                   wo + b * CC * CC,
                                                   (b == 2) ? (float*)d_out : a_cur);
    }
}